// Round 1
// 138.150 us; speedup vs baseline: 1.1606x; 1.1606x over previous
//
#include <hip/hip_runtime.h>

// Problem constants
static constexpr int NB   = 128;   // batch
static constexpr int NCIN = 64;    // input channels
static constexpr int NG   = 8;     // groups
static constexpr int NH   = 14;    // spatial
static constexpr int NP   = 16;    // mixed width
static constexpr int NJ   = 32;    // conv out channels
static constexpr int HH   = NH * NH;       // 196
static constexpr int LROW = 20;    // padded LDS row (l in [-2,17])

// ---------------------------------------------------------------------------
// Kernel 1: channel mix.  t4[bg][ml][p] = sum_j x[b][j][g][ml]*wmix[j][p]
// One spatial position per thread -> 200,704 threads = 3136 waves = 12/CU
// (was 784 waves = 3/CU, latency-bound). Lanes read consecutive dwords
// (fully coalesced); wmix accesses wave-uniform -> s_load.
// ---------------------------------------------------------------------------
__global__ __launch_bounds__(256) void mix_kernel(const float* __restrict__ x,
                                                  const float* __restrict__ wmix,
                                                  float* __restrict__ t4) {
    int gid = blockIdx.x * 256 + threadIdx.x;    // 0 .. 200703
    int ml  = gid % HH;                          // spatial position
    int bg  = gid / HH;                          // b*8 + g
    int b   = bg >> 3;
    int g   = bg & 7;

    float acc[NP];
#pragma unroll
    for (int p = 0; p < NP; p++) acc[p] = 0.f;

    const float* xb = x + (size_t)b * (NCIN * NG * HH) + (size_t)g * HH + ml;

#pragma unroll 4
    for (int j = 0; j < NCIN; j++) {
        float xv = xb[(size_t)j * (NG * HH)];
#pragma unroll
        for (int p = 0; p < NP; p++) acc[p] += xv * wmix[j * NP + p];   // uniform -> s_load
    }

    float* tb = t4 + (size_t)gid * NP;   // gid == bg*196 + ml exactly
#pragma unroll
    for (int p4 = 0; p4 < 4; p4++) {
        *reinterpret_cast<float4*>(tb + p4 * 4) =
            make_float4(acc[p4 * 4 + 0], acc[p4 * 4 + 1],
                        acc[p4 * 4 + 2], acc[p4 * 4 + 3]);
    }
}

// ---------------------------------------------------------------------------
// Kernel 2: 5-tap grouped conv along l + roll + output transpose.
// block = (b, o); 256 threads, lane = (p, jh); each thread owns j = 2jh, 2jh+1.
// LDS cut to 17,408 B (output staged in two 256-channel halves reusing the
// t4s/w2s region) -> 7 blocks/CU resident (was 5 at 30,720 B), 28 waves/CU.
// out[b][(j*16+p)][o][n] = sum_{g,d} t4[b][g][o_src][n+d-2][p] * W2[g][d][j]
//   - (n==0)  correction wconv[g][0][2][j]*t4[l=0]
//   - (n==13) correction wconv[g][2][0][j]*t4[l=13]
// ---------------------------------------------------------------------------
__global__ __launch_bounds__(256) void conv_kernel(const float* __restrict__ t4,
                                                   const float* __restrict__ wconv,
                                                   float* __restrict__ out) {
    __shared__ __align__(16) float lds[4352];      // 17,408 B
    float* t4s = lds;               // [8][16][LROW] = 2560 floats
    float* w2s = lds + 2560;        // [8][5][32]    = 1280 floats
    float* wcs = lds + 3840;        // [2][8][32]    =  512 floats
    // output staging (per half): 256*15 = 3840 floats, reuses lds[0..3840)

    const int tid   = threadIdx.x;
    const int b     = blockIdx.x / NH;
    const int o     = blockIdx.x % NH;
    const int o_src = (o + NH - 1) % NH;

    // ---- stage t4 slice: 448 float4 loads (1792 floats), transposed LDS write ----
    const float4* tsl4 = reinterpret_cast<const float4*>(
        t4 + ((size_t)b * NG * HH + (size_t)o_src * NH) * NP);
#pragma unroll
    for (int r = 0; r < 2; r++) {
        int idx = r * 256 + tid;
        if (idx < 448) {
            int g  = idx / 56;
            int rr = idx % 56;                     // float4 within g-slice
            int l  = rr >> 2;                      // row 0..13
            int p0 = (rr & 3) * 4;                 // p base 0,4,8,12
            float4 v = tsl4[(size_t)g * (HH * NP / 4) + rr];
            t4s[(g * 16 + p0 + 0) * LROW + (l + 2)] = v.x;
            t4s[(g * 16 + p0 + 1) * LROW + (l + 2)] = v.y;
            t4s[(g * 16 + p0 + 2) * LROW + (l + 2)] = v.z;
            t4s[(g * 16 + p0 + 3) * LROW + (l + 2)] = v.w;
        }
    }
    // zero pads: l2 in {0,1,16,17,18,19} for all 128 (g,p) rows
#pragma unroll
    for (int r = 0; r < 3; r++) {                  // 768 entries
        int idx = r * 256 + tid;
        int gp  = idx / 6;
        int s   = idx % 6;
        int l2  = (s < 2) ? s : (14 + s);
        t4s[gp * LROW + l2] = 0.f;
    }
    // W2[g][d][j] = sum_{i+k==d} wconv[g][i][k][j]
#pragma unroll
    for (int r = 0; r < 5; r++) {                  // 1280 entries
        int idx = r * 256 + tid;
        int g   = idx / 160;
        int di  = (idx / 32) % 5;
        int j   = idx % 32;
        int ilo = di > 2 ? di - 2 : 0;
        int ihi = di < 2 ? di : 2;
        float s = 0.f;
        for (int i = ilo; i <= ihi; i++) {
            int k = di - i;
            s += wconv[((g * 3 + i) * 3 + k) * 32 + j];
        }
        w2s[idx] = s;
    }
    // corrections: wcs[0][g][j] = wconv[g][0][2][j]; wcs[1][g][j] = wconv[g][2][0][j]
#pragma unroll
    for (int r = 0; r < 2; r++) {                  // 512 entries
        int idx = r * 256 + tid;
        int sel = idx / 256;
        int g   = (idx / 32) % 8;
        int j   = idx % 32;
        wcs[idx] = wconv[(g * 9 + (sel ? 6 : 2)) * 32 + j];
    }
    __syncthreads();

    const int p  = tid & 15;
    const int jh = tid >> 4;        // 0..15
    const int jb = jh * 2;          // this thread's channels: j = jb, jb+1

    float acc[NH][2];
#pragma unroll
    for (int n = 0; n < NH; n++) { acc[n][0] = 0.f; acc[n][1] = 0.f; }

    for (int g = 0; g < NG; g++) {
        float row[LROW];
        const float* rp = &t4s[(g * 16 + p) * LROW];
#pragma unroll
        for (int q = 0; q < 5; q++) {
            float4 v = *reinterpret_cast<const float4*>(rp + q * 4);
            row[q * 4 + 0] = v.x; row[q * 4 + 1] = v.y;
            row[q * 4 + 2] = v.z; row[q * 4 + 3] = v.w;
        }
#pragma unroll
        for (int di = 0; di < 5; di++) {
            float2 w = *reinterpret_cast<const float2*>(&w2s[(g * 5 + di) * 32 + jb]);
#pragma unroll
            for (int n = 0; n < NH; n++) {
                float rv = row[n + di];
                acc[n][0] += rv * w.x;
                acc[n][1] += rv * w.y;
            }
        }
        float2 c0 = *reinterpret_cast<const float2*>(&wcs[g * 32 + jb]);
        float2 c1 = *reinterpret_cast<const float2*>(&wcs[256 + g * 32 + jb]);
        float r2 = row[2], r15 = row[15];
        acc[0][0]  -= r2  * c0.x; acc[0][1]  -= r2  * c0.y;
        acc[13][0] -= r15 * c1.x; acc[13][1] -= r15 * c1.y;
    }

    __syncthreads();   // done reading t4s/w2s/wcs; reuse lds as output stage

    // ---- write out in two 256-channel halves (keeps LDS at 3840 floats) ----
    float* obase = out + (size_t)b * 512 * HH + (size_t)o * NH;
#pragma unroll
    for (int h = 0; h < 2; h++) {
        if ((jh >> 3) == h) {                      // this thread's channels in half h
#pragma unroll
            for (int jj = 0; jj < 2; jj++) {
                int cl = (jb + jj) * 16 + p - h * 256;   // local channel 0..255
#pragma unroll
                for (int n = 0; n < NH; n++) lds[cl * 15 + n] = acc[n][jj];
            }
        }
        __syncthreads();
        float* ob = obase + (size_t)(h * 256) * HH;
#pragma unroll
        for (int r = 0; r < 14; r++) {             // 3584 = 256*14
            int idx = r * 256 + tid;
            int c   = idx / 14;
            int n   = idx % 14;
            ob[(size_t)c * HH + n] = lds[c * 15 + n];
        }
        __syncthreads();
    }
}

extern "C" void kernel_launch(void* const* d_in, const int* in_sizes, int n_in,
                              void* d_out, int out_size, void* d_ws, size_t ws_size,
                              hipStream_t stream) {
    const float* x     = (const float*)d_in[0];
    const float* wconv = (const float*)d_in[1];
    const float* wmix  = (const float*)d_in[2];
    float* out = (float*)d_out;
    float* t4  = (float*)d_ws;   // 128*8*196*16 floats = 12.85 MB scratch

    // Kernel 1: 200,704 threads = 784 blocks * 256
    mix_kernel<<<784, 256, 0, stream>>>(x, wmix, t4);
    // Kernel 2: one block per (b, o), 256 threads
    conv_kernel<<<NB * NH, 256, 0, stream>>>(t4, wconv, out);
}